// Round 1
// baseline (669.741 us; speedup 1.0000x reference)
//
#include <hip/hip_runtime.h>

#define FEAT 128
#define HID  100

// ---------------- runtime int32/int64 edge-index detection ----------------
__device__ __forceinline__ int get_edge(const void* ei, int f64, long long pos) {
    return f64 ? (int)((const long long*)ei)[pos] : ((const int*)ei)[pos];
}

__global__ void k_detect(const void* ei, int* flag) {
    // if edge_index staged as int64, every odd int32 word (high half) is 0
    const int* p = (const int*)ei;
    int is64 = 1;
    for (int i = 0; i < 64; i++)
        if (p[2 * i + 1] != 0) { is64 = 0; break; }
    *flag = is64;
}

// ---------------- degree / dinv / CSR build ----------------
__global__ void k_init(float* deg, int* counts, int* cursor, int N) {
    int i = blockIdx.x * blockDim.x + threadIdx.x;
    if (i < N) { deg[i] = 1.0f; counts[i] = 0; cursor[i] = 0; }  // self-loop weight 1
}

__global__ void k_deg(const void* ei, const float* w, const int* flag,
                      float* deg, int* counts, int E) {
    int e = blockIdx.x * blockDim.x + threadIdx.x;
    if (e >= E) return;
    int f64 = *flag;
    int d = get_edge(ei, f64, (long long)E + e);
    atomicAdd(&deg[d], w[e]);
    atomicAdd(&counts[d], 1);
}

__global__ void k_dinv(const float* deg, float* dinv, int N) {
    int i = blockIdx.x * blockDim.x + threadIdx.x;
    if (i < N) dinv[i] = rsqrtf(deg[i]);
}

__global__ void k_scan1(const int* counts, int* offs, int* partials, int N) {
    __shared__ int lds[1024];
    int t = threadIdx.x;
    int idx = blockIdx.x * 1024 + t;
    int v = (idx < N) ? counts[idx] : 0;
    lds[t] = v;
    __syncthreads();
    for (int off = 1; off < 1024; off <<= 1) {
        int tv = (t >= off) ? lds[t - off] : 0;
        __syncthreads();
        lds[t] += tv;
        __syncthreads();
    }
    if (idx < N) offs[idx] = lds[t] - v;  // exclusive
    if (t == 1023) partials[blockIdx.x] = lds[1023];
}

__global__ void k_scan2(int* partials, int nb) {
    __shared__ int lds[128];
    int t = threadIdx.x;
    int v = (t < nb) ? partials[t] : 0;
    lds[t] = v;
    __syncthreads();
    for (int off = 1; off < 128; off <<= 1) {
        int tv = (t >= off) ? lds[t - off] : 0;
        __syncthreads();
        lds[t] += tv;
        __syncthreads();
    }
    if (t < nb) partials[t] = lds[t] - v;  // exclusive block bases
}

__global__ void k_scan3(int* offs, const int* partials, int N) {
    int idx = blockIdx.x * 1024 + threadIdx.x;
    if (idx < N) offs[idx] += partials[blockIdx.x];
}

__global__ void k_fill(const void* ei, const float* w, const int* flag, const float* dinv,
                       const int* offs, int* cursor, int* csr_src, float* csr_norm, int E) {
    int e = blockIdx.x * blockDim.x + threadIdx.x;
    if (e >= E) return;
    int f64 = *flag;
    int s = get_edge(ei, f64, e);
    int d = get_edge(ei, f64, (long long)E + e);
    float nr = dinv[s] * w[e] * dinv[d];
    int pos = offs[d] + atomicAdd(&cursor[d], 1);
    csr_src[pos]  = s;
    csr_norm[pos] = nr;
}

// ---------------- aggregation: one wave per node, atomic-free ----------------
__global__ __launch_bounds__(256)
void k_agg(const float* __restrict__ x, const float* __restrict__ dinv,
           const int* __restrict__ offs, const int* __restrict__ counts,
           const int* __restrict__ csr_src, const float* __restrict__ csr_norm,
           float* __restrict__ aggx, int N) {
    int wid  = __builtin_amdgcn_readfirstlane(threadIdx.x >> 6);
    int lane = threadIdx.x & 63;
    int node = blockIdx.x * 4 + wid;
    if (node >= N) return;
    float dn = dinv[node];
    float sn = dn * dn;  // self-loop norm = 1/deg
    float2 acc = *(const float2*)(x + (size_t)node * FEAT + lane * 2);
    acc.x *= sn; acc.y *= sn;
    int rs  = offs[node];
    int cnt = counts[node];
    for (int i = 0; i < cnt; i++) {
        int   s  = csr_src[rs + i];
        float nr = csr_norm[rs + i];
        float2 xv = *(const float2*)(x + (size_t)s * FEAT + lane * 2);
        acc.x += nr * xv.x;
        acc.y += nr * xv.y;
    }
    *(float2*)(aggx + (size_t)node * FEAT + lane * 2) = acc;
}

// ---------------- fused GEMM + gate + output, 64 nodes per block ----------------
__global__ __launch_bounds__(256)
void k_post(const float* __restrict__ aggx,
            const float* __restrict__ Wcz, const float* __restrict__ bcz,
            const float* __restrict__ Wch, const float* __restrict__ bch,
            const float* __restrict__ Wlz, const float* __restrict__ blz,
            const float* __restrict__ Wlh, const float* __restrict__ blh,
            const float* __restrict__ Wout, const float* __restrict__ bout,
            float* __restrict__ out, int N) {
    __shared__ float c_lds[200 * 64];
    __shared__ float red[256];
    int t = threadIdx.x;
    int lane = t & 63;
    int g = __builtin_amdgcn_readfirstlane(t >> 6);  // wave-uniform group 0..3
    int n = blockIdx.x * 64 + lane;

    // Phase A: c[n, 0:200] = aggx[n,:] @ [Wcz | Wch] + [bcz | bch]
    // group 0: Wcz cols 0..49, g1: Wcz 50..99, g2: Wch 0..49, g3: Wch 50..99
    const float* W    = (g < 2) ? Wcz : Wch;
    const float* bias = (g < 2) ? bcz : bch;
    int co = (g & 1) * 50;
    float acc[50];
#pragma unroll
    for (int c = 0; c < 50; c++) acc[c] = 0.f;
    const float* arow = aggx + (size_t)n * FEAT;
    for (int j4 = 0; j4 < FEAT / 4; j4++) {
        float4 a;
        if (n < N) a = *(const float4*)(arow + j4 * 4);
        else       a = make_float4(0.f, 0.f, 0.f, 0.f);
#pragma unroll
        for (int jj = 0; jj < 4; jj++) {
            float aj = (&a.x)[jj];
            const float* wr = W + (j4 * 4 + jj) * HID + co;
#pragma unroll
            for (int c = 0; c < 50; c++) acc[c] += aj * wr[c];
        }
    }
    int colbase = g * 50;
#pragma unroll
    for (int c = 0; c < 50; c++)
        c_lds[(colbase + c) * 64 + lane] = acc[c] + bias[co + c];
    __syncthreads();

    // Phase B: z = sigmoid(cz @ Wlz_top + blz), ht = tanh(ch @ Wlh_top + blh)
    int kb = g * 25;
    float az[25], ah[25];
#pragma unroll
    for (int k = 0; k < 25; k++) { az[k] = 0.f; ah[k] = 0.f; }
    for (int j = 0; j < HID; j++) {
        float czj = c_lds[j * 64 + lane];
        float chj = c_lds[(HID + j) * 64 + lane];
        const float* wz = Wlz + j * HID + kb;
        const float* wh = Wlh + j * HID + kb;
#pragma unroll
        for (int k = 0; k < 25; k++) {
            az[k] += czj * wz[k];
            ah[k] += chj * wh[k];
        }
    }
    float partial = 0.f;
#pragma unroll
    for (int k = 0; k < 25; k++) {
        float zv = 1.f / (1.f + expf(-(az[k] + blz[kb + k])));
        float ht = tanhf(ah[k] + blh[kb + k]);
        float h  = (1.f - zv) * ht;          // Hn = (1-Z)*Ht  (H0 = 0)
        h = h > 0.f ? h : 0.f;               // relu
        partial += h * Wout[kb + k];
    }
    red[t] = partial;
    __syncthreads();
    if (g == 0 && n < N)
        out[n] = red[lane] + red[64 + lane] + red[128 + lane] + red[192 + lane] + bout[0];
}

// ---------------- launcher ----------------
extern "C" void kernel_launch(void* const* d_in, const int* in_sizes, int n_in,
                              void* d_out, int out_size, void* d_ws, size_t ws_size,
                              hipStream_t stream) {
    const float* x    = (const float*)d_in[0];
    const void*  ei   = d_in[1];
    const float* ew   = (const float*)d_in[2];
    const float* Wcz  = (const float*)d_in[3];
    const float* bcz  = (const float*)d_in[4];
    // d_in[5], d_in[6] (Wcr, bcr) are dead: R only multiplies H0 == 0
    const float* Wch  = (const float*)d_in[7];
    const float* bch  = (const float*)d_in[8];
    const float* Wlz  = (const float*)d_in[9];
    const float* blz  = (const float*)d_in[10];
    // d_in[11], d_in[12] (Wlr, blr) dead too
    const float* Wlh  = (const float*)d_in[13];
    const float* blh  = (const float*)d_in[14];
    const float* Wout = (const float*)d_in[15];
    const float* bout = (const float*)d_in[16];
    float* out = (float*)d_out;

    int N = in_sizes[0] / FEAT;   // 100000
    int E = in_sizes[2];          // 1600000

    // workspace partition (256B aligned); total ~66 MB
    char* p = (char*)d_ws;
    auto alloc = [&](size_t bytes) -> char* {
        char* r = p;
        p += (bytes + 255) & ~(size_t)255;
        return r;
    };
    int*   flag     = (int*)  alloc(256);
    float* deg      = (float*)alloc((size_t)N * 4);
    float* dinv     = (float*)alloc((size_t)N * 4);
    int*   counts   = (int*)  alloc((size_t)N * 4);
    int*   cursor   = (int*)  alloc((size_t)N * 4);
    int*   offs     = (int*)  alloc((size_t)N * 4);
    int*   partials = (int*)  alloc(512);
    int*   csr_src  = (int*)  alloc((size_t)E * 4);
    float* csr_norm = (float*)alloc((size_t)E * 4);
    float* aggx     = (float*)alloc((size_t)N * FEAT * 4);

    int nb = (N + 1023) / 1024;  // 98 (<=128 for scan2)

    k_detect<<<1, 1, 0, stream>>>(ei, flag);
    k_init<<<(N + 255) / 256, 256, 0, stream>>>(deg, counts, cursor, N);
    k_deg<<<(E + 255) / 256, 256, 0, stream>>>(ei, ew, flag, deg, counts, E);
    k_dinv<<<(N + 255) / 256, 256, 0, stream>>>(deg, dinv, N);
    k_scan1<<<nb, 1024, 0, stream>>>(counts, offs, partials, N);
    k_scan2<<<1, 128, 0, stream>>>(partials, nb);
    k_scan3<<<nb, 1024, 0, stream>>>(offs, partials, N);
    k_fill<<<(E + 255) / 256, 256, 0, stream>>>(ei, ew, flag, dinv, offs, cursor,
                                                csr_src, csr_norm, E);
    k_agg<<<(N + 3) / 4, 256, 0, stream>>>(x, dinv, offs, counts, csr_src, csr_norm,
                                           aggx, N);
    k_post<<<(N + 63) / 64, 256, 0, stream>>>(aggx, Wcz, bcz, Wch, bch,
                                              Wlz, blz, Wlh, blh, Wout, bout, out, N);
}

// Round 2
// 578.579 us; speedup vs baseline: 1.1576x; 1.1576x over previous
//
#include <hip/hip_runtime.h>

#define FEAT 128
#define HID  100

// ---------------- runtime int32/int64 edge-index detection ----------------
__device__ __forceinline__ int get_edge(const void* ei, int f64, long long pos) {
    return f64 ? (int)((const long long*)ei)[pos] : ((const int*)ei)[pos];
}

__global__ void k_detect(const void* ei, int* flag) {
    // one wave: if staged as int64, all sampled high words are 0
    int t = threadIdx.x;
    const int* p = (const int*)ei;
    unsigned long long b = __ballot(p[2 * t + 1] == 0);
    if (t == 0) *flag = (b == ~0ull) ? 1 : 0;
}

// ---------------- degree / dinv / CSR build ----------------
__global__ void k_init(float* deg, int* counts, int* cursor, int N) {
    int i = blockIdx.x * blockDim.x + threadIdx.x;
    if (i < N) { deg[i] = 1.0f; counts[i] = 0; cursor[i] = 0; }  // self-loop weight 1
}

__global__ void k_deg(const void* ei, const float* w, const int* flag,
                      float* deg, int* counts, int E) {
    int e = blockIdx.x * blockDim.x + threadIdx.x;
    if (e >= E) return;
    int f64 = *flag;
    int d = get_edge(ei, f64, (long long)E + e);
    atomicAdd(&deg[d], w[e]);
    atomicAdd(&counts[d], 1);
}

__global__ void k_dinv(const float* deg, float* dinv, int N) {
    int i = blockIdx.x * blockDim.x + threadIdx.x;
    if (i < N) dinv[i] = rsqrtf(deg[i]);
}

__global__ void k_scan1(const int* counts, int* offs, int* partials, int N) {
    __shared__ int lds[1024];
    int t = threadIdx.x;
    int idx = blockIdx.x * 1024 + t;
    int v = (idx < N) ? counts[idx] : 0;
    lds[t] = v;
    __syncthreads();
    for (int off = 1; off < 1024; off <<= 1) {
        int tv = (t >= off) ? lds[t - off] : 0;
        __syncthreads();
        lds[t] += tv;
        __syncthreads();
    }
    if (idx < N) offs[idx] = lds[t] - v;  // exclusive
    if (t == 1023) partials[blockIdx.x] = lds[1023];
}

__global__ void k_scan2(int* partials, int nb) {
    __shared__ int lds[128];
    int t = threadIdx.x;
    int v = (t < nb) ? partials[t] : 0;
    lds[t] = v;
    __syncthreads();
    for (int off = 1; off < 128; off <<= 1) {
        int tv = (t >= off) ? lds[t - off] : 0;
        __syncthreads();
        lds[t] += tv;
        __syncthreads();
    }
    if (t < nb) partials[t] = lds[t] - v;  // exclusive block bases
}

__global__ void k_scan3(int* offs, const int* partials, int N) {
    int idx = blockIdx.x * 1024 + threadIdx.x;
    if (idx < N) offs[idx] += partials[blockIdx.x];
}

__global__ void k_fill(const void* ei, const float* w, const int* flag, const float* dinv,
                       const int* offs, int* cursor, int2* csr, int E) {
    int e = blockIdx.x * blockDim.x + threadIdx.x;
    if (e >= E) return;
    int f64 = *flag;
    int s = get_edge(ei, f64, e);
    int d = get_edge(ei, f64, (long long)E + e);
    float nr = dinv[s] * w[e] * dinv[d];
    int pos = offs[d] + atomicAdd(&cursor[d], 1);
    csr[pos] = make_int2(s, __float_as_int(nr));
}

// ---------------- aggregation: wave per node, 4 edges in flight ----------------
__global__ __launch_bounds__(256)
void k_agg2(const float* __restrict__ x, const float* __restrict__ dinv,
            const int* __restrict__ offs, const int* __restrict__ counts,
            const int2* __restrict__ csr, float* __restrict__ aggx, int N) {
    int wid  = __builtin_amdgcn_readfirstlane(threadIdx.x >> 6);
    int lane = threadIdx.x & 63;
    long long node = (long long)blockIdx.x * 4 + wid;
    if (node >= N) return;
    int q  = lane >> 4;        // edge slot 0..3
    int fl = lane & 15;        // feature group: floats fl*8 .. fl*8+7
    float acc[8];
#pragma unroll
    for (int j = 0; j < 8; j++) acc[j] = 0.f;
    int rs  = offs[node];
    int cnt = counts[node];
    for (int i = q; i < cnt; i += 4) {   // wave reads csr[rs+4n .. rs+4n+3] per pass
        int2 e = csr[rs + i];
        float nr = __int_as_float(e.y);
        const float* xp = x + (size_t)e.x * FEAT + fl * 8;
        float4 v0 = *(const float4*)xp;
        float4 v1 = *(const float4*)(xp + 4);
        acc[0] += nr * v0.x; acc[1] += nr * v0.y;
        acc[2] += nr * v0.z; acc[3] += nr * v0.w;
        acc[4] += nr * v1.x; acc[5] += nr * v1.y;
        acc[6] += nr * v1.z; acc[7] += nr * v1.w;
    }
#pragma unroll
    for (int j = 0; j < 8; j++) {
        acc[j] += __shfl_xor(acc[j], 16);
        acc[j] += __shfl_xor(acc[j], 32);
    }
    if (q == 0) {
        float dn = dinv[node];
        float sn = dn * dn;  // self-loop norm = 1/deg
        const float* xs = x + (size_t)node * FEAT + fl * 8;
        float4 s0 = *(const float4*)xs;
        float4 s1 = *(const float4*)(xs + 4);
        acc[0] += sn * s0.x; acc[1] += sn * s0.y;
        acc[2] += sn * s0.z; acc[3] += sn * s0.w;
        acc[4] += sn * s1.x; acc[5] += sn * s1.y;
        acc[6] += sn * s1.z; acc[7] += sn * s1.w;
        float* op = aggx + (size_t)node * FEAT + fl * 8;
        *(float4*)op       = make_float4(acc[0], acc[1], acc[2], acc[3]);
        *(float4*)(op + 4) = make_float4(acc[4], acc[5], acc[6], acc[7]);
    }
}

// ---------------- weight folding: Wz' = Wcz@Wlz_top, Wh' = Wch@Wlh_top ----------
// Wfold[128][200]: cols 0..99 -> z path, 100..199 -> h path. bfold[200] likewise.
__global__ __launch_bounds__(256)
void k_fold(const float* __restrict__ Wcz, const float* __restrict__ bcz,
            const float* __restrict__ Wch, const float* __restrict__ bch,
            const float* __restrict__ Wlz, const float* __restrict__ blz,
            const float* __restrict__ Wlh, const float* __restrict__ blh,
            float* __restrict__ Wfold, float* __restrict__ bfold) {
    int idx = blockIdx.x * 256 + threadIdx.x;
    if (idx < FEAT * 200) {
        int j = idx / 200, c = idx % 200;
        const float* A = (c < HID) ? Wcz : Wch;
        const float* B = (c < HID) ? Wlz : Wlh;
        int cc = (c < HID) ? c : c - HID;
        float acc = 0.f;
        for (int m = 0; m < HID; m++) acc += A[j * HID + m] * B[m * HID + cc];
        Wfold[idx] = acc;
    } else if (idx < FEAT * 200 + 200) {
        int c = idx - FEAT * 200;
        const float* bc = (c < HID) ? bcz : bch;
        const float* B  = (c < HID) ? Wlz : Wlh;
        const float* bl = (c < HID) ? blz : blh;
        int cc = (c < HID) ? c : c - HID;
        float acc = bl[cc];
        for (int j = 0; j < HID; j++) acc += bc[j] * B[j * HID + cc];
        bfold[c] = acc;
    }
}

// ---------------- fused GEMM + gates + output, 64 nodes per block --------------
__global__ __launch_bounds__(256, 4)
void k_post2(const float* __restrict__ aggx, const float* __restrict__ Wfold,
             const float* __restrict__ bfold, const float* __restrict__ Wout,
             const float* __restrict__ bout, float* __restrict__ out, int N) {
    __shared__ float smem[64 * 129];   // A-tile (padded), then reused for ht exchange
    __shared__ float red[128];
    int t = threadIdx.x;
    int lane = t & 63;                 // node within tile
    int gu = __builtin_amdgcn_readfirstlane(t >> 6);  // col group 0..3
    long long node = (long long)blockIdx.x * 64 + lane;

    // stage A tile [64][128] -> smem row-padded to 129 (conflict-free reads)
    for (int it = 0; it < 16; it++) {
        int idx = it * 256 + t;        // float2 slot 0..4095
        int n = idx >> 6, j2 = idx & 63;
        long long nn = (long long)blockIdx.x * 64 + n;
        float2 v = make_float2(0.f, 0.f);
        if (nn < N) v = *(const float2*)(aggx + nn * FEAT + j2 * 2);
        smem[n * 129 + j2 * 2]     = v.x;
        smem[n * 129 + j2 * 2 + 1] = v.y;
    }
    __syncthreads();

    // acc[c] = A[node,:] @ Wfold[:, co+c]   (group gu covers cols gu*50..gu*50+49)
    int co = gu * 50;
    float acc[50];
#pragma unroll
    for (int c = 0; c < 50; c++) acc[c] = 0.f;
    for (int kc = 0; kc < 4; kc++) {
        float a_reg[32];
#pragma unroll
        for (int i = 0; i < 32; i++) a_reg[i] = smem[lane * 129 + kc * 32 + i];
#pragma unroll 2
        for (int j = 0; j < 32; j++) {
            const float* wr = Wfold + (kc * 32 + j) * 200 + co;   // wave-uniform
            float aj = a_reg[j];
#pragma unroll
            for (int c = 0; c < 50; c++) acc[c] += aj * wr[c];
        }
    }
    __syncthreads();   // done with A-tile region

    // groups 2,3: ht = tanh(ah + bh) -> smem[k][node]
    if (gu >= 2) {
        int kb = (gu - 2) * 50;
#pragma unroll
        for (int c = 0; c < 50; c++) {
            float ht = tanhf(acc[c] + bfold[100 + kb + c]);
            smem[(kb + c) * 64 + lane] = ht;
        }
    }
    __syncthreads();

    // groups 0,1: z = sigmoid(az + bz); h = relu((1-z)*ht); partial dot with Wout
    if (gu < 2) {
        int kb = gu * 50;
        float partial = 0.f;
#pragma unroll
        for (int c = 0; c < 50; c++) {
            float z = 1.f / (1.f + expf(-(acc[c] + bfold[kb + c])));
            float h = (1.f - z) * smem[(kb + c) * 64 + lane];
            h = h > 0.f ? h : 0.f;
            partial += h * Wout[kb + c];
        }
        red[gu * 64 + lane] = partial;
    }
    __syncthreads();
    if (gu == 0 && node < N)
        out[node] = red[lane] + red[64 + lane] + bout[0];
}

// ---------------- launcher ----------------
extern "C" void kernel_launch(void* const* d_in, const int* in_sizes, int n_in,
                              void* d_out, int out_size, void* d_ws, size_t ws_size,
                              hipStream_t stream) {
    const float* x    = (const float*)d_in[0];
    const void*  ei   = d_in[1];
    const float* ew   = (const float*)d_in[2];
    const float* Wcz  = (const float*)d_in[3];
    const float* bcz  = (const float*)d_in[4];
    // d_in[5], d_in[6] (Wcr, bcr) dead: R only multiplies H0 == 0
    const float* Wch  = (const float*)d_in[7];
    const float* bch  = (const float*)d_in[8];
    const float* Wlz  = (const float*)d_in[9];
    const float* blz  = (const float*)d_in[10];
    // d_in[11], d_in[12] (Wlr, blr) dead too
    const float* Wlh  = (const float*)d_in[13];
    const float* blh  = (const float*)d_in[14];
    const float* Wout = (const float*)d_in[15];
    const float* bout = (const float*)d_in[16];
    float* out = (float*)d_out;

    int N = in_sizes[0] / FEAT;   // 100000
    int E = in_sizes[2];          // 1600000

    // workspace partition (256B aligned)
    char* p = (char*)d_ws;
    auto alloc = [&](size_t bytes) -> char* {
        char* r = p;
        p += (bytes + 255) & ~(size_t)255;
        return r;
    };
    int*   flag     = (int*)  alloc(256);
    float* deg      = (float*)alloc((size_t)N * 4);
    float* dinv     = (float*)alloc((size_t)N * 4);
    int*   counts   = (int*)  alloc((size_t)N * 4);
    int*   cursor   = (int*)  alloc((size_t)N * 4);
    int*   offs     = (int*)  alloc((size_t)N * 4);
    int*   partials = (int*)  alloc(512);
    int2*  csr      = (int2*) alloc((size_t)E * 8);
    float* aggx     = (float*)alloc((size_t)N * FEAT * 4);
    float* Wfold    = (float*)alloc((size_t)FEAT * 200 * 4);
    float* bfold    = (float*)alloc(200 * 4);

    int nb = (N + 1023) / 1024;  // 98 (<=128 for scan2)

    k_detect<<<1, 64, 0, stream>>>(ei, flag);
    k_init<<<(N + 255) / 256, 256, 0, stream>>>(deg, counts, cursor, N);
    k_deg<<<(E + 255) / 256, 256, 0, stream>>>(ei, ew, flag, deg, counts, E);
    k_dinv<<<(N + 255) / 256, 256, 0, stream>>>(deg, dinv, N);
    k_scan1<<<nb, 1024, 0, stream>>>(counts, offs, partials, N);
    k_scan2<<<1, 128, 0, stream>>>(partials, nb);
    k_scan3<<<nb, 1024, 0, stream>>>(offs, partials, N);
    k_fill<<<(E + 255) / 256, 256, 0, stream>>>(ei, ew, flag, dinv, offs, cursor, csr, E);
    k_agg2<<<(N + 3) / 4, 256, 0, stream>>>(x, dinv, offs, counts, csr, aggx, N);
    k_fold<<<(FEAT * 200 + 200 + 255) / 256, 256, 0, stream>>>(
        Wcz, bcz, Wch, bch, Wlz, blz, Wlh, blh, Wfold, bfold);
    k_post2<<<(N + 63) / 64, 256, 0, stream>>>(aggx, Wfold, bfold, Wout, bout, out, N);
}

// Round 3
// 455.270 us; speedup vs baseline: 1.4711x; 1.2708x over previous
//
#include <hip/hip_runtime.h>

#define FEAT 128
#define HID  100

// ---------------- runtime int32/int64 edge-index detection ----------------
__device__ __forceinline__ int get_edge(const void* ei, int f64, long long pos) {
    return f64 ? (int)((const long long*)ei)[pos] : ((const int*)ei)[pos];
}

__global__ void k_detect(const void* ei, int* flag) {
    // one wave: if staged as int64, all sampled high words are 0
    int t = threadIdx.x;
    const int* p = (const int*)ei;
    unsigned long long b = __ballot(p[2 * t + 1] == 0);
    if (t == 0) *flag = (b == ~0ull) ? 1 : 0;
}

// ---------------- CSR build: histogram returns rank (1 atomic/edge total) -----
__global__ void k_deg2(const void* ei, const int* flag, int* counts, int* rank, int E) {
    int e = blockIdx.x * blockDim.x + threadIdx.x;
    if (e >= E) return;
    int f64 = *flag;
    int d = get_edge(ei, f64, (long long)E + e);
    rank[e] = atomicAdd(&counts[d], 1);   // rank within dst; counts = histogram
}

__global__ void k_scan1(const int* counts, int* offs, int* partials, int N) {
    __shared__ int lds[1024];
    int t = threadIdx.x;
    int idx = blockIdx.x * 1024 + t;
    int v = (idx < N) ? counts[idx] : 0;
    lds[t] = v;
    __syncthreads();
    for (int off = 1; off < 1024; off <<= 1) {
        int tv = (t >= off) ? lds[t - off] : 0;
        __syncthreads();
        lds[t] += tv;
        __syncthreads();
    }
    if (idx < N) offs[idx] = lds[t] - v;  // exclusive
    if (t == 1023) partials[blockIdx.x] = lds[1023];
}

__global__ void k_scan2(int* partials, int nb) {
    __shared__ int lds[128];
    int t = threadIdx.x;
    int v = (t < nb) ? partials[t] : 0;
    lds[t] = v;
    __syncthreads();
    for (int off = 1; off < 128; off <<= 1) {
        int tv = (t >= off) ? lds[t - off] : 0;
        __syncthreads();
        lds[t] += tv;
        __syncthreads();
    }
    if (t < nb) partials[t] = lds[t] - v;  // exclusive block bases
}

__global__ void k_scan3(int* offs, const int* partials, int N) {
    int idx = blockIdx.x * 1024 + threadIdx.x;
    if (idx < N) offs[idx] += partials[blockIdx.x];
}

// fill CSR with raw (src, w) — atomic-free, no dinv dependency
__global__ void k_fill2(const void* ei, const float* w, const int* flag,
                        const int* offs, const int* rank, int2* csr, int E) {
    int e = blockIdx.x * blockDim.x + threadIdx.x;
    if (e >= E) return;
    int f64 = *flag;
    int s = get_edge(ei, f64, e);
    int d = get_edge(ei, f64, (long long)E + e);
    int pos = offs[d] + rank[e];
    csr[pos] = make_int2(s, __float_as_int(w[e]));
}

// deg[node] = 1 + sum of w over CSR row; dinv = rsqrt. 16 lanes per node.
__global__ __launch_bounds__(256)
void k_degsum(const int2* __restrict__ csr, const int* __restrict__ offs,
              const int* __restrict__ counts, float* __restrict__ dinv, int N) {
    int t = threadIdx.x;
    int sub = t & 15;
    long long node = (long long)blockIdx.x * 16 + (t >> 4);
    if (node >= N) return;
    int rs = offs[node], cnt = counts[node];
    float s = 0.f;
    for (int i = sub; i < cnt; i += 16) s += __int_as_float(csr[rs + i].y);
    s += __shfl_xor(s, 1);
    s += __shfl_xor(s, 2);
    s += __shfl_xor(s, 4);
    s += __shfl_xor(s, 8);
    if (sub == 0) dinv[node] = rsqrtf(1.f + s);
}

// ---------------- aggregation: wave per node, 8 edges in flight ----------------
// aggx[dst] = dinv[dst] * ( sum_e w_e*dinv[src_e]*x[src_e] + dinv[dst]*x[dst] )
__global__ __launch_bounds__(256)
void k_agg3(const float* __restrict__ x, const float* __restrict__ dinv,
            const int* __restrict__ offs, const int* __restrict__ counts,
            const int2* __restrict__ csr, float* __restrict__ aggx, int N) {
    int wid  = __builtin_amdgcn_readfirstlane(threadIdx.x >> 6);
    int lane = threadIdx.x & 63;
    long long node = (long long)blockIdx.x * 4 + wid;
    if (node >= N) return;
    int q  = lane >> 3;        // edge slot 0..7
    int fl = lane & 7;         // feature group: floats fl*16 .. fl*16+15
    float acc[16];
#pragma unroll
    for (int j = 0; j < 16; j++) acc[j] = 0.f;
    int rs  = offs[node];
    int cnt = counts[node];
    for (int i = q; i < cnt; i += 8) {
        int2 e = csr[rs + i];
        float nr = __int_as_float(e.y) * dinv[e.x];   // w * dinv[src]
        const float* xp = x + (size_t)e.x * FEAT + fl * 16;
        float4 v0 = *(const float4*)xp;
        float4 v1 = *(const float4*)(xp + 4);
        float4 v2 = *(const float4*)(xp + 8);
        float4 v3 = *(const float4*)(xp + 12);
        acc[0]  += nr * v0.x; acc[1]  += nr * v0.y; acc[2]  += nr * v0.z; acc[3]  += nr * v0.w;
        acc[4]  += nr * v1.x; acc[5]  += nr * v1.y; acc[6]  += nr * v1.z; acc[7]  += nr * v1.w;
        acc[8]  += nr * v2.x; acc[9]  += nr * v2.y; acc[10] += nr * v2.z; acc[11] += nr * v2.w;
        acc[12] += nr * v3.x; acc[13] += nr * v3.y; acc[14] += nr * v3.z; acc[15] += nr * v3.w;
    }
#pragma unroll
    for (int j = 0; j < 16; j++) {
        acc[j] += __shfl_xor(acc[j], 8);
        acc[j] += __shfl_xor(acc[j], 16);
        acc[j] += __shfl_xor(acc[j], 32);
    }
    if (q == 0) {
        float dn = dinv[node];
        const float* xs = x + (size_t)node * FEAT + fl * 16;
        float4 s0 = *(const float4*)xs;
        float4 s1 = *(const float4*)(xs + 4);
        float4 s2 = *(const float4*)(xs + 8);
        float4 s3 = *(const float4*)(xs + 12);
        acc[0]  += dn * s0.x; acc[1]  += dn * s0.y; acc[2]  += dn * s0.z; acc[3]  += dn * s0.w;
        acc[4]  += dn * s1.x; acc[5]  += dn * s1.y; acc[6]  += dn * s1.z; acc[7]  += dn * s1.w;
        acc[8]  += dn * s2.x; acc[9]  += dn * s2.y; acc[10] += dn * s2.z; acc[11] += dn * s2.w;
        acc[12] += dn * s3.x; acc[13] += dn * s3.y; acc[14] += dn * s3.z; acc[15] += dn * s3.w;
#pragma unroll
        for (int j = 0; j < 16; j++) acc[j] *= dn;
        float* op = aggx + (size_t)node * FEAT + fl * 16;
        *(float4*)op        = make_float4(acc[0],  acc[1],  acc[2],  acc[3]);
        *(float4*)(op + 4)  = make_float4(acc[4],  acc[5],  acc[6],  acc[7]);
        *(float4*)(op + 8)  = make_float4(acc[8],  acc[9],  acc[10], acc[11]);
        *(float4*)(op + 12) = make_float4(acc[12], acc[13], acc[14], acc[15]);
    }
}

// ---------------- weight folding: Wz' = Wcz@Wlz_top, Wh' = Wch@Wlh_top ----------
// Wfold[128][200]: cols 0..99 -> z path, 100..199 -> h path. bfold[200] likewise.
__global__ __launch_bounds__(256)
void k_fold(const float* __restrict__ Wcz, const float* __restrict__ bcz,
            const float* __restrict__ Wch, const float* __restrict__ bch,
            const float* __restrict__ Wlz, const float* __restrict__ blz,
            const float* __restrict__ Wlh, const float* __restrict__ blh,
            float* __restrict__ Wfold, float* __restrict__ bfold) {
    int idx = blockIdx.x * 256 + threadIdx.x;
    if (idx < FEAT * 200) {
        int j = idx / 200, c = idx % 200;
        const float* A = (c < HID) ? Wcz : Wch;
        const float* B = (c < HID) ? Wlz : Wlh;
        int cc = (c < HID) ? c : c - HID;
        float acc = 0.f;
        for (int m = 0; m < HID; m++) acc += A[j * HID + m] * B[m * HID + cc];
        Wfold[idx] = acc;
    } else if (idx < FEAT * 200 + 200) {
        int c = idx - FEAT * 200;
        const float* bc = (c < HID) ? bcz : bch;
        const float* B  = (c < HID) ? Wlz : Wlh;
        const float* bl = (c < HID) ? blz : blh;
        int cc = (c < HID) ? c : c - HID;
        float acc = bl[cc];
        for (int j = 0; j < HID; j++) acc += bc[j] * B[j * HID + cc];
        bfold[c] = acc;
    }
}

// ---------------- fused GEMM + gates + output, 64 nodes per block --------------
__global__ __launch_bounds__(256, 4)
void k_post2(const float* __restrict__ aggx, const float* __restrict__ Wfold,
             const float* __restrict__ bfold, const float* __restrict__ Wout,
             const float* __restrict__ bout, float* __restrict__ out, int N) {
    __shared__ float smem[64 * 129];   // A-tile (padded), then reused for ht exchange
    __shared__ float red[128];
    int t = threadIdx.x;
    int lane = t & 63;                 // node within tile
    int gu = __builtin_amdgcn_readfirstlane(t >> 6);  // col group 0..3
    long long node = (long long)blockIdx.x * 64 + lane;

    // stage A tile [64][128] -> smem row-padded to 129 (conflict-free reads)
    for (int it = 0; it < 16; it++) {
        int idx = it * 256 + t;        // float2 slot 0..4095
        int n = idx >> 6, j2 = idx & 63;
        long long nn = (long long)blockIdx.x * 64 + n;
        float2 v = make_float2(0.f, 0.f);
        if (nn < N) v = *(const float2*)(aggx + nn * FEAT + j2 * 2);
        smem[n * 129 + j2 * 2]     = v.x;
        smem[n * 129 + j2 * 2 + 1] = v.y;
    }
    __syncthreads();

    // acc[c] = A[node,:] @ Wfold[:, co+c]   (group gu covers cols gu*50..gu*50+49)
    int co = gu * 50;
    float acc[50];
#pragma unroll
    for (int c = 0; c < 50; c++) acc[c] = 0.f;
    for (int kc = 0; kc < 4; kc++) {
        float a_reg[32];
#pragma unroll
        for (int i = 0; i < 32; i++) a_reg[i] = smem[lane * 129 + kc * 32 + i];
#pragma unroll 2
        for (int j = 0; j < 32; j++) {
            const float* wr = Wfold + (kc * 32 + j) * 200 + co;   // wave-uniform
            float aj = a_reg[j];
#pragma unroll
            for (int c = 0; c < 50; c++) acc[c] += aj * wr[c];
        }
    }
    __syncthreads();   // done with A-tile region

    // groups 2,3: ht = tanh(ah + bh) -> smem[k][node]
    if (gu >= 2) {
        int kb = (gu - 2) * 50;
#pragma unroll
        for (int c = 0; c < 50; c++) {
            float ht = tanhf(acc[c] + bfold[100 + kb + c]);
            smem[(kb + c) * 64 + lane] = ht;
        }
    }
    __syncthreads();

    // groups 0,1: z = sigmoid(az + bz); h = relu((1-z)*ht); partial dot with Wout
    if (gu < 2) {
        int kb = gu * 50;
        float partial = 0.f;
#pragma unroll
        for (int c = 0; c < 50; c++) {
            float z = 1.f / (1.f + expf(-(acc[c] + bfold[kb + c])));
            float h = (1.f - z) * smem[(kb + c) * 64 + lane];
            h = h > 0.f ? h : 0.f;
            partial += h * Wout[kb + c];
        }
        red[gu * 64 + lane] = partial;
    }
    __syncthreads();
    if (gu == 0 && node < N)
        out[node] = red[lane] + red[64 + lane] + bout[0];
}

// ---------------- launcher ----------------
extern "C" void kernel_launch(void* const* d_in, const int* in_sizes, int n_in,
                              void* d_out, int out_size, void* d_ws, size_t ws_size,
                              hipStream_t stream) {
    const float* x    = (const float*)d_in[0];
    const void*  ei   = d_in[1];
    const float* ew   = (const float*)d_in[2];
    const float* Wcz  = (const float*)d_in[3];
    const float* bcz  = (const float*)d_in[4];
    // d_in[5], d_in[6] (Wcr, bcr) dead: R only multiplies H0 == 0
    const float* Wch  = (const float*)d_in[7];
    const float* bch  = (const float*)d_in[8];
    const float* Wlz  = (const float*)d_in[9];
    const float* blz  = (const float*)d_in[10];
    // d_in[11], d_in[12] (Wlr, blr) dead too
    const float* Wlh  = (const float*)d_in[13];
    const float* blh  = (const float*)d_in[14];
    const float* Wout = (const float*)d_in[15];
    const float* bout = (const float*)d_in[16];
    float* out = (float*)d_out;

    int N = in_sizes[0] / FEAT;   // 100000
    int E = in_sizes[2];          // 1600000

    // workspace partition (256B aligned)
    char* p = (char*)d_ws;
    auto alloc = [&](size_t bytes) -> char* {
        char* r = p;
        p += (bytes + 255) & ~(size_t)255;
        return r;
    };
    int*   flag     = (int*)  alloc(256);
    float* dinv     = (float*)alloc((size_t)N * 4);
    int*   counts   = (int*)  alloc((size_t)N * 4);
    int*   offs     = (int*)  alloc((size_t)N * 4);
    int*   partials = (int*)  alloc(512);
    int2*  csr      = (int2*) alloc((size_t)E * 8);
    float* aggx     = (float*)alloc((size_t)N * FEAT * 4);
    float* Wfold    = (float*)alloc((size_t)FEAT * 200 * 4);
    float* bfold    = (float*)alloc(200 * 4);
    // rank[e] aliases aggx: rank is dead before k_agg3 writes aggx (disjoint lifetimes)
    int*   rank     = (int*)aggx;

    int nb = (N + 1023) / 1024;  // 98 (<=128 for scan2)

    k_detect<<<1, 64, 0, stream>>>(ei, flag);
    hipMemsetAsync(counts, 0, (size_t)N * 4, stream);
    k_deg2<<<(E + 255) / 256, 256, 0, stream>>>(ei, flag, counts, rank, E);
    k_scan1<<<nb, 1024, 0, stream>>>(counts, offs, partials, N);
    k_scan2<<<1, 128, 0, stream>>>(partials, nb);
    k_scan3<<<nb, 1024, 0, stream>>>(offs, partials, N);
    k_fill2<<<(E + 255) / 256, 256, 0, stream>>>(ei, ew, flag, offs, rank, csr, E);
    k_degsum<<<(N + 15) / 16, 256, 0, stream>>>(csr, offs, counts, dinv, N);
    k_agg3<<<(N + 3) / 4, 256, 0, stream>>>(x, dinv, offs, counts, csr, aggx, N);
    k_fold<<<(FEAT * 200 + 200 + 255) / 256, 256, 0, stream>>>(
        Wcz, bcz, Wch, bch, Wlz, blz, Wlh, blh, Wfold, bfold);
    k_post2<<<(N + 63) / 64, 256, 0, stream>>>(aggx, Wfold, bfold, Wout, bout, out, N);
}

// Round 5
// 352.646 us; speedup vs baseline: 1.8992x; 1.2910x over previous
//
#include <hip/hip_runtime.h>

#define FEAT 128
#define HID  100

typedef __attribute__((ext_vector_type(8))) short short8;
typedef __attribute__((ext_vector_type(4))) float f32x4;

// RNE f32 -> bf16
__device__ __forceinline__ unsigned short f2bf(float f) {
    union { float f; unsigned int u; } v; v.f = f;
    unsigned int r = v.u + 0x7fffu + ((v.u >> 16) & 1u);
    return (unsigned short)(r >> 16);
}

// ---------------- runtime int32/int64 edge-index detection ----------------
__device__ __forceinline__ int get_edge(const void* ei, int f64, long long pos) {
    return f64 ? (int)((const long long*)ei)[pos] : ((const int*)ei)[pos];
}

__global__ void k_detect(const void* ei, int* flag) {
    int t = threadIdx.x;
    const int* p = (const int*)ei;
    unsigned long long b = __ballot(p[2 * t + 1] == 0);
    if (t == 0) *flag = (b == ~0ull) ? 1 : 0;
}

// ---------------- x (f32) -> xb (bf16) ----------------
__global__ __launch_bounds__(256)
void k_cvt(const float* __restrict__ x, uint4* __restrict__ xb, int n8) {
    int stride = gridDim.x * blockDim.x;
    for (int i = blockIdx.x * blockDim.x + threadIdx.x; i < n8; i += stride) {
        float4 a = *(const float4*)(x + (size_t)i * 8);
        float4 b = *(const float4*)(x + (size_t)i * 8 + 4);
        uint4 o;
        o.x = f2bf(a.x) | ((unsigned)f2bf(a.y) << 16);
        o.y = f2bf(a.z) | ((unsigned)f2bf(a.w) << 16);
        o.z = f2bf(b.x) | ((unsigned)f2bf(b.y) << 16);
        o.w = f2bf(b.z) | ((unsigned)f2bf(b.w) << 16);
        xb[i] = o;
    }
}

// ---------------- CSR build: histogram returns rank (1 atomic/edge) ----------
__global__ void k_deg2(const void* ei, const int* flag, int* counts, int* rank, int E) {
    int e = blockIdx.x * blockDim.x + threadIdx.x;
    if (e >= E) return;
    int f64 = *flag;
    int d = get_edge(ei, f64, (long long)E + e);
    rank[e] = atomicAdd(&counts[d], 1);
}

__global__ void k_scan1(const int* counts, int* offs, int* partials, int N) {
    __shared__ int lds[1024];
    int t = threadIdx.x;
    int idx = blockIdx.x * 1024 + t;
    int v = (idx < N) ? counts[idx] : 0;
    lds[t] = v;
    __syncthreads();
    for (int off = 1; off < 1024; off <<= 1) {
        int tv = (t >= off) ? lds[t - off] : 0;
        __syncthreads();
        lds[t] += tv;
        __syncthreads();
    }
    if (idx < N) offs[idx] = lds[t] - v;
    if (t == 1023) partials[blockIdx.x] = lds[1023];
}

__global__ void k_scan2(int* partials, int nb) {
    __shared__ int lds[128];
    int t = threadIdx.x;
    int v = (t < nb) ? partials[t] : 0;
    lds[t] = v;
    __syncthreads();
    for (int off = 1; off < 128; off <<= 1) {
        int tv = (t >= off) ? lds[t - off] : 0;
        __syncthreads();
        lds[t] += tv;
        __syncthreads();
    }
    if (t < nb) partials[t] = lds[t] - v;
}

__global__ void k_scan3(int* offs, const int* partials, int N) {
    int idx = blockIdx.x * 1024 + threadIdx.x;
    if (idx < N) offs[idx] += partials[blockIdx.x];
}

__global__ void k_fill2(const void* ei, const float* w, const int* flag,
                        const int* offs, const int* rank, int2* csr, int E) {
    int e = blockIdx.x * blockDim.x + threadIdx.x;
    if (e >= E) return;
    int f64 = *flag;
    int s = get_edge(ei, f64, e);
    int d = get_edge(ei, f64, (long long)E + e);
    int pos = offs[d] + rank[e];
    csr[pos] = make_int2(s, __float_as_int(w[e]));
}

// deg[node] = 1 + sum w over CSR row; dinv = rsqrt. 16 lanes per node.
__global__ __launch_bounds__(256)
void k_degsum(const int2* __restrict__ csr, const int* __restrict__ offs,
              const int* __restrict__ counts, float* __restrict__ dinv, int N) {
    int t = threadIdx.x;
    int sub = t & 15;
    long long node = (long long)blockIdx.x * 16 + (t >> 4);
    if (node >= N) return;
    int rs = offs[node], cnt = counts[node];
    float s = 0.f;
    for (int i = sub; i < cnt; i += 16) s += __int_as_float(csr[rs + i].y);
    s += __shfl_xor(s, 1);
    s += __shfl_xor(s, 2);
    s += __shfl_xor(s, 4);
    s += __shfl_xor(s, 8);
    if (sub == 0) dinv[node] = rsqrtf(1.f + s);
}

// ---------------- aggregation: wave/node, 8 edges in flight, bf16 gathers -----
// aggx[d] = dinv[d]*( sum_e w_e*dinv[s_e]*x[s_e] + dinv[d]*x[d] ), stored bf16
__global__ __launch_bounds__(256)
void k_agg4(const unsigned short* __restrict__ xb, const float* __restrict__ dinv,
            const int* __restrict__ offs, const int* __restrict__ counts,
            const int2* __restrict__ csr, unsigned short* __restrict__ aggx, int N) {
    int wid  = __builtin_amdgcn_readfirstlane(threadIdx.x >> 6);
    int lane = threadIdx.x & 63;
    long long node = (long long)blockIdx.x * 4 + wid;
    if (node >= N) return;
    int q  = lane >> 3;        // edge slot 0..7
    int fl = lane & 7;         // feature group: floats fl*16 .. fl*16+15
    float acc[16];
#pragma unroll
    for (int j = 0; j < 16; j++) acc[j] = 0.f;
    int rs  = offs[node];
    int cnt = counts[node];
    for (int i = q; i < cnt; i += 8) {
        int2 e = csr[rs + i];
        float nr = __int_as_float(e.y) * dinv[e.x];   // w * dinv[src]
        const uint4* xp = (const uint4*)(xb + (size_t)e.x * FEAT + fl * 16);
        uint4 v0 = xp[0];
        uint4 v1 = xp[1];
        const unsigned* u0 = &v0.x;
        const unsigned* u1 = &v1.x;
#pragma unroll
        for (int j = 0; j < 4; j++) {
            acc[2*j]     += nr * __uint_as_float(u0[j] << 16);
            acc[2*j + 1] += nr * __uint_as_float(u0[j] & 0xffff0000u);
            acc[8 + 2*j]     += nr * __uint_as_float(u1[j] << 16);
            acc[8 + 2*j + 1] += nr * __uint_as_float(u1[j] & 0xffff0000u);
        }
    }
#pragma unroll
    for (int j = 0; j < 16; j++) {
        acc[j] += __shfl_xor(acc[j], 8);
        acc[j] += __shfl_xor(acc[j], 16);
        acc[j] += __shfl_xor(acc[j], 32);
    }
    if (q == 0) {
        float dn = dinv[node];
        const uint4* xs = (const uint4*)(xb + (size_t)node * FEAT + fl * 16);
        uint4 s0 = xs[0];
        uint4 s1 = xs[1];
        const unsigned* u0 = &s0.x;
        const unsigned* u1 = &s1.x;
#pragma unroll
        for (int j = 0; j < 4; j++) {
            acc[2*j]     += dn * __uint_as_float(u0[j] << 16);
            acc[2*j + 1] += dn * __uint_as_float(u0[j] & 0xffff0000u);
            acc[8 + 2*j]     += dn * __uint_as_float(u1[j] << 16);
            acc[8 + 2*j + 1] += dn * __uint_as_float(u1[j] & 0xffff0000u);
        }
        uint4 o0, o1;
        unsigned* p0 = &o0.x;
        unsigned* p1 = &o1.x;
#pragma unroll
        for (int j = 0; j < 4; j++) {
            p0[j] = f2bf(acc[2*j] * dn)     | ((unsigned)f2bf(acc[2*j+1] * dn) << 16);
            p1[j] = f2bf(acc[8+2*j] * dn)   | ((unsigned)f2bf(acc[8+2*j+1] * dn) << 16);
        }
        uint4* op = (uint4*)(aggx + (size_t)node * FEAT + fl * 16);
        op[0] = o0;
        op[1] = o1;
    }
}

// ---------------- weight folding into MFMA-B-fragment order -------------------
// Logical B[k][n], k=0..127, n=0..255: n<100 -> (Wcz@Wlz)[k][n]; 128<=n<228 ->
// (Wch@Wlh)[k][n-128]; else 0.  Packed bf16 at ushort pos:
//   ((ni*4+ks)*64 + hi*16 + lc)*8 + j   with ni=n>>4, lc=n&15, ks=k>>5,
//   hi=(k>>3)&3, j=k&7  — exactly the 16x16x32 B-fragment lane order.
__global__ __launch_bounds__(256)
void k_fold2(const float* __restrict__ Wcz, const float* __restrict__ bcz,
             const float* __restrict__ Wch, const float* __restrict__ bch,
             const float* __restrict__ Wlz, const float* __restrict__ blz,
             const float* __restrict__ Wlh, const float* __restrict__ blh,
             const float* __restrict__ Wout,
             unsigned short* __restrict__ WB, float* __restrict__ bfold_ext,
             float* __restrict__ WoutZ) {
    int idx = blockIdx.x * 256 + threadIdx.x;
    if (idx < FEAT * 256) {
        int k = idx >> 8, n = idx & 255;
        float val = 0.f;
        if (n < HID) {
            for (int m = 0; m < HID; m++) val += Wcz[k * HID + m] * Wlz[m * HID + n];
        } else if (n >= 128 && n < 128 + HID) {
            int c = n - 128;
            for (int m = 0; m < HID; m++) val += Wch[k * HID + m] * Wlh[m * HID + c];
        }
        int ni = n >> 4, lc = n & 15, ks = k >> 5, hi = (k >> 3) & 3, j = k & 7;
        WB[(((ni * 4 + ks) * 64 + hi * 16 + lc) << 3) + j] = f2bf(val);
    } else if (idx < FEAT * 256 + 256) {
        int c = idx - FEAT * 256;
        float v = 0.f;
        if (c < HID) {
            v = blz[c];
            for (int j = 0; j < HID; j++) v += bcz[j] * Wlz[j * HID + c];
        } else if (c >= 128 && c < 128 + HID) {
            int cc = c - 128;
            v = blh[cc];
            for (int j = 0; j < HID; j++) v += bch[j] * Wlh[j * HID + cc];
        }
        bfold_ext[c] = v;
    } else if (idx < FEAT * 256 + 256 + 128) {
        int c = idx - FEAT * 256 - 256;
        WoutZ[c] = (c < HID) ? Wout[c] : 0.f;
    }
}

// ---------------- MFMA GEMM + gates + output, 64 nodes per block --------------
// D[64][256] = A[64][128] @ B[128][256]; cols 0..127 z-path, 128..255 h-path.
// Wave w owns col-tiles {2w, 2w+1, 2w+8, 2w+9} so z and its h partner share a lane.
__global__ __launch_bounds__(256)
void k_post3(const unsigned short* __restrict__ aggx, const unsigned short* __restrict__ WB,
             const float* __restrict__ bfold_ext, const float* __restrict__ WoutZ,
             const float* __restrict__ bout, float* __restrict__ out, int N) {
    __shared__ unsigned short At[64 * 136];   // 128 + 8 pad (272B rows: 2-way bank max)
    __shared__ float red[64 * 4];
    int t = threadIdx.x;
    int lane = t & 63;
    int w = __builtin_amdgcn_readfirstlane(t >> 6);
    long long base = (long long)blockIdx.x * 64;

    // stage A tile: 64 rows x 16 uint4
    for (int it = 0; it < 4; it++) {
        int idx = it * 256 + t;
        int row = idx >> 4, c16 = idx & 15;
        long long grow = base + row;
        uint4 v = make_uint4(0u, 0u, 0u, 0u);
        if (grow < N) v = *(const uint4*)(aggx + grow * FEAT + c16 * 8);
        *(uint4*)(At + row * 136 + c16 * 8) = v;
    }
    __syncthreads();

    int l15 = lane & 15, lhi = lane >> 4;
    int tadd = 2 * w;
    f32x4 acc[4][4];   // [tileIdx][mi]
#pragma unroll
    for (int ti = 0; ti < 4; ti++)
#pragma unroll
        for (int mi = 0; mi < 4; mi++) acc[ti][mi] = (f32x4)0.f;

    const int tiles[4] = {tadd, tadd + 1, tadd + 8, tadd + 9};
#pragma unroll
    for (int ks = 0; ks < 4; ks++) {
        short8 a[4];
#pragma unroll
        for (int mi = 0; mi < 4; mi++)
            a[mi] = *(const short8*)(At + (mi * 16 + l15) * 136 + ks * 32 + lhi * 8);
        short8 b[4];
#pragma unroll
        for (int ti = 0; ti < 4; ti++)
            b[ti] = *(const short8*)(WB + (((tiles[ti] * 4 + ks) * 64 + lane) << 3));
#pragma unroll
        for (int ti = 0; ti < 4; ti++)
#pragma unroll
            for (int mi = 0; mi < 4; mi++)
                acc[ti][mi] = __builtin_amdgcn_mfma_f32_16x16x32_bf16(
                    a[mi], b[ti], acc[ti][mi], 0, 0, 0);
    }

    // epilogue: pair z tile delta with h tile delta+2 (same lane, col+128)
    float partial[4][4];
#pragma unroll
    for (int mi = 0; mi < 4; mi++)
#pragma unroll
        for (int r = 0; r < 4; r++) partial[mi][r] = 0.f;
#pragma unroll
    for (int d = 0; d < 2; d++) {
        int zcol = (tadd + d) * 16 + l15;       // 0..127
        float bz = bfold_ext[zcol];
        float bh = bfold_ext[zcol + 128];
        float wo = WoutZ[zcol];
#pragma unroll
        for (int mi = 0; mi < 4; mi++)
#pragma unroll
            for (int r = 0; r < 4; r++) {
                float az = acc[d][mi][r] + bz;
                float ah = acc[d + 2][mi][r] + bh;
                float z  = 1.f / (1.f + expf(-az));
                float ht = tanhf(ah);
                float h  = (1.f - z) * ht;
                h = h > 0.f ? h : 0.f;
                partial[mi][r] += h * wo;
            }
    }
#pragma unroll
    for (int mi = 0; mi < 4; mi++)
#pragma unroll
        for (int r = 0; r < 4; r++) {
            float p = partial[mi][r];
            p += __shfl_xor(p, 1);
            p += __shfl_xor(p, 2);
            p += __shfl_xor(p, 4);
            p += __shfl_xor(p, 8);
            partial[mi][r] = p;
        }
    if (l15 == 0) {
#pragma unroll
        for (int mi = 0; mi < 4; mi++)
#pragma unroll
            for (int r = 0; r < 4; r++)
                red[(mi * 16 + lhi * 4 + r) * 4 + w] = partial[mi][r];
    }
    __syncthreads();
    if (t < 64) {
        long long node = base + t;
        if (node < N)
            out[node] = red[t * 4] + red[t * 4 + 1] + red[t * 4 + 2] + red[t * 4 + 3]
                      + bout[0];
    }
}

// ---------------- launcher ----------------
extern "C" void kernel_launch(void* const* d_in, const int* in_sizes, int n_in,
                              void* d_out, int out_size, void* d_ws, size_t ws_size,
                              hipStream_t stream) {
    const float* x    = (const float*)d_in[0];
    const void*  ei   = d_in[1];
    const float* ew   = (const float*)d_in[2];
    const float* Wcz  = (const float*)d_in[3];
    const float* bcz  = (const float*)d_in[4];
    // d_in[5], d_in[6] (Wcr, bcr) dead: R only multiplies H0 == 0
    const float* Wch  = (const float*)d_in[7];
    const float* bch  = (const float*)d_in[8];
    const float* Wlz  = (const float*)d_in[9];
    const float* blz  = (const float*)d_in[10];
    // d_in[11], d_in[12] (Wlr, blr) dead too
    const float* Wlh  = (const float*)d_in[13];
    const float* blh  = (const float*)d_in[14];
    const float* Wout = (const float*)d_in[15];
    const float* bout = (const float*)d_in[16];
    float* out = (float*)d_out;

    int N = in_sizes[0] / FEAT;   // 100000
    int E = in_sizes[2];          // 1600000

    char* p = (char*)d_ws;
    auto alloc = [&](size_t bytes) -> char* {
        char* r = p;
        p += (bytes + 255) & ~(size_t)255;
        return r;
    };
    int*            flag      = (int*)  alloc(256);
    float*          dinv      = (float*)alloc((size_t)N * 4);
    int*            counts    = (int*)  alloc((size_t)N * 4);
    int*            offs      = (int*)  alloc((size_t)N * 4);
    int*            partials  = (int*)  alloc(512);
    int2*           csr       = (int2*) alloc((size_t)E * 8);
    unsigned short* xb        = (unsigned short*)alloc((size_t)N * FEAT * 2);
    unsigned short* aggx      = (unsigned short*)alloc((size_t)N * FEAT * 2);
    unsigned short* WB        = (unsigned short*)alloc((size_t)FEAT * 256 * 2);
    float*          bfold_ext = (float*)alloc(256 * 4);
    float*          WoutZ     = (float*)alloc(128 * 4);
    // rank aliases aggx: rank dead before k_agg4 writes aggx
    int*            rank      = (int*)aggx;

    int nb = (N + 1023) / 1024;  // 98 (<=128 for scan2)

    k_detect<<<1, 64, 0, stream>>>(ei, flag);
    hipMemsetAsync(counts, 0, (size_t)N * 4, stream);
    k_cvt<<<1024, 256, 0, stream>>>(x, (uint4*)xb, N * FEAT / 8);
    k_deg2<<<(E + 255) / 256, 256, 0, stream>>>(ei, flag, counts, rank, E);
    k_scan1<<<nb, 1024, 0, stream>>>(counts, offs, partials, N);
    k_scan2<<<1, 128, 0, stream>>>(partials, nb);
    k_scan3<<<nb, 1024, 0, stream>>>(offs, partials, N);
    k_fill2<<<(E + 255) / 256, 256, 0, stream>>>(ei, ew, flag, offs, rank, csr, E);
    k_degsum<<<(N + 15) / 16, 256, 0, stream>>>(csr, offs, counts, dinv, N);
    k_agg4<<<(N + 3) / 4, 256, 0, stream>>>(xb, dinv, offs, counts, csr, aggx, N);
    k_fold2<<<(FEAT * 256 + 256 + 128 + 255) / 256, 256, 0, stream>>>(
        Wcz, bcz, Wch, bch, Wlz, blz, Wlh, blh, Wout, WB, bfold_ext, WoutZ);
    k_post3<<<(N + 63) / 64, 256, 0, stream>>>(aggx, WB, bfold_ext, WoutZ, bout, out, N);
}